// Round 9
// baseline (3388.416 us; speedup 1.0000x reference)
//
#include <hip/hip_runtime.h>

#define HH 64
#define TT 2048
#define BB 256
#define YSZ (BB*TT)   // y elements before hT in d_out

typedef __attribute__((ext_vector_type(8))) short bf16x8;        // MFMA A/B frag (4 regs)
typedef __attribute__((ext_vector_type(4))) float f32x4;         // MFMA C/D frag
typedef __attribute__((ext_vector_type(4))) unsigned int u32x4;

__device__ __forceinline__ float sigmoid_f(float v) { return 1.0f/(1.0f+__expf(-v)); }
__device__ __forceinline__ float tanh_f(float v)    { return 1.0f - 2.0f/(1.0f+__expf(2.0f*v)); }

// D += A*B with A sourced from AGPRs (weights pinned there: zero per-iter cost,
// non-rematerializable -- the legal form of what R6 attempted; ISA section 10).
__device__ __forceinline__ void MFMA(f32x4& d, const bf16x8& a, const bf16x8& b) {
    asm("v_mfma_f32_16x16x32_bf16 %0, %1, %2, %0" : "+v"(d) : "a"(a), "v"(b));
}
// Pin a value into AGPR(s): opaque def, whole live range in the (otherwise
// empty) AGPR class. R7-proven mechanism.
#define PIN8(v)  asm("" : "+a"(v))
#define PINF(v)  asm("" : "+a"(v))

// Split two fp32 into bf16 hi-pair (truncation) + lo-pair (RNE of residual).
// Pair layout: low16 = even row, high16 = odd row (matches frag k-pair order).
__device__ __forceinline__ void split_pair(float a0, float a1, unsigned& hi, unsigned& lo) {
    unsigned u0 = __float_as_uint(a0) & 0xFFFF0000u;
    unsigned u1 = __float_as_uint(a1) & 0xFFFF0000u;
    hi = (u0 >> 16) | u1;
    float l0 = a0 - __uint_as_float(u0);
    float l1 = a1 - __uint_as_float(u1);
    asm("v_cvt_pk_bf16_f32 %0, %1, %2" : "=v"(lo) : "v"(l0), "v"(l1));
}

// Build hi/lo A-fragments for one (tile,k-half): lane holds row (lane&15),
// k = kh*32 + (lane>>4)*8 + jj  (same k-mapping used for B -> permutation-safe).
__device__ __forceinline__ void load_frag_pair(const float* Wrow, bf16x8& hi8, bf16x8& lo8) {
    #pragma unroll
    for (int jj = 0; jj < 8; ++jj) {
        float f = Wrow[jj];
        unsigned uh = __float_as_uint(f) & 0xFFFF0000u;
        hi8[jj] = (short)(uh >> 16);
        float lo = f - __uint_as_float(uh);
        unsigned ul = __float_as_uint(lo);
        unsigned rr = ul + 0x7FFFu + ((ul >> 16) & 1u);
        lo8[jj] = (short)(rr >> 16);
    }
}

// 256 threads = 4 waves (1/SIMD), 256 blocks (1 seq/CU). Wave j owns gate-row
// triples {16j..16j+16} of r/z/n blocks for all 3 gate matrices + head tile j
// -> every combine is lane-local on the MFMA D-fragments (col=lane&15 is a
// replicated/redundant dim; rows = (lane>>4)*4 + reg, m89-verified layout).
// One barrier per iteration: h state double-buffered in LDS as bf16 hi/lo
// pairs; exact fp32 h carried in registers by its owner lanes.
__global__ __launch_bounds__(256, 1)
void gru_fused(const float* __restrict__ x,      // [B,T,1]
               const float* __restrict__ h0in,   // [2,B,H]
               const float* __restrict__ W_ih0,  // [192,1]
               const float* __restrict__ W_hh0,  // [192,64]
               const float* __restrict__ b_ih0,  // [192]
               const float* __restrict__ b_hh0,  // [192]
               const float* __restrict__ W_ih1,  // [192,64]
               const float* __restrict__ W_hh1,  // [192,64]
               const float* __restrict__ b_ih1,  // [192]
               const float* __restrict__ b_hh1,  // [192]
               const float* __restrict__ Wh1,    // [64,64]
               const float* __restrict__ bh1,    // [64]
               const float* __restrict__ Wh2,    // [1,64]
               const float* __restrict__ bh2,    // [1]
               float* __restrict__ out)          // y [B*T] ++ hT [2,B,H]
{
    const int b    = blockIdx.x;
    const int tid  = threadIdx.x;
    const int j    = tid >> 6;        // wave 0..3
    const int lane = tid & 63;
    const int g    = lane >> 4;       // k-chunk / row-group 0..3
    const int c    = lane & 15;       // MFMA col (replicated dim)

    // h state, double-buffered, packed bf16 pairs: [buf][layer][hi/lo][pair m/2]
    __shared__ __align__(16) unsigned int hpk[2][2][2][32];
    __shared__ float yp[2][4];        // head partials, double-buffered

    // ---- weight fragments -> AGPRs ----
    // fA=W_hh0, fX=W_ih1, fG=W_hh1 (12 each: [tile]*4 + [khalf]*2 + [hi/lo]),
    // fH=Wh1 (4). Tile t rowbase = 64*t + 16*j (r/z/n triple locality).
    bf16x8 fA[12], fX[12], fG[12], fH[4];
    #pragma unroll
    for (int t = 0; t < 3; ++t)
        #pragma unroll
        for (int kh = 0; kh < 2; ++kh) {
            const size_t ro = (size_t)(64*t + 16*j + c) * HH + kh*32 + g*8;
            load_frag_pair(W_hh0 + ro, fA[t*4+kh*2], fA[t*4+kh*2+1]);
            load_frag_pair(W_ih1 + ro, fX[t*4+kh*2], fX[t*4+kh*2+1]);
            load_frag_pair(W_hh1 + ro, fG[t*4+kh*2], fG[t*4+kh*2+1]);
        }
    #pragma unroll
    for (int kh = 0; kh < 2; ++kh)
        load_frag_pair(Wh1 + (size_t)(16*j + c) * HH + kh*32 + g*8,
                       fH[kh*2], fH[kh*2+1]);
    #pragma unroll
    for (int i = 0; i < 12; ++i) { PIN8(fA[i]); PIN8(fX[i]); PIN8(fG[i]); }
    #pragma unroll
    for (int i = 0; i < 4; ++i) PIN8(fH[i]);

    // ---- per-lane constants (AGPR-pinned; compiler re-reads per use) ----
    float bA[12], bX[12], bG[12], bH4[4];
    #pragma unroll
    for (int t = 0; t < 3; ++t)
        #pragma unroll
        for (int r = 0; r < 4; ++r) {
            const int row = 64*t + 16*j + g*4 + r;
            bA[t*4+r] = b_hh0[row];
            bX[t*4+r] = b_ih1[row];
            bG[t*4+r] = b_hh1[row];
        }
    float wR[4], wZ[4], wN[4], bR[4], bZ[4], bN[4], wh2c[4];
    #pragma unroll
    for (int r = 0; r < 4; ++r) {
        const int m = 16*j + g*4 + r;
        bH4[r]  = bh1[m];
        wR[r] = W_ih0[m];      bR[r] = b_ih0[m];
        wZ[r] = W_ih0[m+64];   bZ[r] = b_ih0[m+64];
        wN[r] = W_ih0[m+128];  bN[r] = b_ih0[m+128];
        wh2c[r] = Wh2[m];
    }
    #pragma unroll
    for (int i = 0; i < 12; ++i) { PINF(bA[i]); PINF(bX[i]); PINF(bG[i]); }
    #pragma unroll
    for (int r = 0; r < 4; ++r) {
        PINF(bH4[r]); PINF(wR[r]); PINF(wZ[r]); PINF(wN[r]);
        PINF(bR[r]);  PINF(bZ[r]); PINF(bN[r]); PINF(wh2c[r]);
    }
    const float bh2v = bh2[0];

    // ---- h state: fp32 in registers (owner: all lanes, redundant over c) ----
    float h0p[4], h1p[4];
    #pragma unroll
    for (int r = 0; r < 4; ++r) {
        h0p[r] = h0in[          b*HH + 16*j + g*4 + r];
        h1p[r] = h0in[BB*HH +   b*HH + 16*j + g*4 + r];
    }
    if (c == 0) {   // initial packed state -> buf 0
        unsigned ph_, pl_;
        const int mp = 8*j + g*2;
        split_pair(h0p[0], h0p[1], ph_, pl_);
        hpk[0][0][0][mp]   = ph_; hpk[0][0][1][mp]   = pl_;
        split_pair(h0p[2], h0p[3], ph_, pl_);
        hpk[0][0][0][mp+1] = ph_; hpk[0][0][1][mp+1] = pl_;
        split_pair(h1p[0], h1p[1], ph_, pl_);
        hpk[0][1][0][mp]   = ph_; hpk[0][1][1][mp]   = pl_;
        split_pair(h1p[2], h1p[3], ph_, pl_);
        hpk[0][1][0][mp+1] = ph_; hpk[0][1][1][mp+1] = pl_;
    }
    __syncthreads();

    // Schedule (R1-proven, shifted): A(ii) MFMAs read h0=z0[ii-1], h1=z1[ii-2];
    // B(ii) commits h1->z1[ii-1] (1<=ii<=TT), h0->z0[ii] (ii<TT);
    // yp written in A(ii) from z1[ii-2]; y[ii-3] finished at A(ii).
    for (int ii = 0; ii <= TT + 2; ++ii) {
        const int buf = ii & 1, nbuf = buf ^ 1;

        // ---------------- Phase A ----------------
        const float xv = x[(size_t)b*TT + (ii < TT ? ii : TT-1)];
        if (tid == 0 && ii >= 3) {
            const int pb = (ii-1) & 1;
            out[(size_t)b*TT + (ii-3)] =
                yp[pb][0] + yp[pb][1] + yp[pb][2] + yp[pb][3] + bh2v;
        }
        // B fragments (broadcast reads; cols replicated -> col-map immune)
        bf16x8 B0h[2], B0l[2], B1h[2], B1l[2];
        #pragma unroll
        for (int kh = 0; kh < 2; ++kh) {
            const int o = kh*16 + g*4;
            B0h[kh] = __builtin_bit_cast(bf16x8, *(const u32x4*)&hpk[buf][0][0][o]);
            B0l[kh] = __builtin_bit_cast(bf16x8, *(const u32x4*)&hpk[buf][0][1][o]);
            B1h[kh] = __builtin_bit_cast(bf16x8, *(const u32x4*)&hpk[buf][1][0][o]);
            B1l[kh] = __builtin_bit_cast(bf16x8, *(const u32x4*)&hpk[buf][1][1][o]);
        }
        // accumulators init = bias (AGPR reads)
        f32x4 aA[3], aX[3], aG[3], aH;
        #pragma unroll
        for (int t = 0; t < 3; ++t) {
            aA[t] = (f32x4){bA[t*4+0], bA[t*4+1], bA[t*4+2], bA[t*4+3]};
            aX[t] = (f32x4){bX[t*4+0], bX[t*4+1], bX[t*4+2], bX[t*4+3]};
            aG[t] = (f32x4){bG[t*4+0], bG[t*4+1], bG[t*4+2], bG[t*4+3]};
        }
        aH = (f32x4){bH4[0], bH4[1], bH4[2], bH4[3]};
        // 3-term split MFMAs: Whi*Hhi + Whi*Hlo + Wlo*Hhi
        #pragma unroll
        for (int t = 0; t < 3; ++t)
            #pragma unroll
            for (int kh = 0; kh < 2; ++kh) {
                const int fi = t*4 + kh*2;
                MFMA(aA[t], fA[fi],   B0h[kh]);
                MFMA(aA[t], fA[fi],   B0l[kh]);
                MFMA(aA[t], fA[fi+1], B0h[kh]);
                MFMA(aX[t], fX[fi],   B0h[kh]);
                MFMA(aX[t], fX[fi],   B0l[kh]);
                MFMA(aX[t], fX[fi+1], B0h[kh]);
                MFMA(aG[t], fG[fi],   B1h[kh]);
                MFMA(aG[t], fG[fi],   B1l[kh]);
                MFMA(aG[t], fG[fi+1], B1h[kh]);
            }
        #pragma unroll
        for (int kh = 0; kh < 2; ++kh) {
            MFMA(aH, fH[kh*2],   B1h[kh]);
            MFMA(aH, fH[kh*2],   B1l[kh]);
            MFMA(aH, fH[kh*2+1], B1h[kh]);
        }
        // head partial: relu dot Wh2, reduce over row-groups
        {
            float p = 0.f;
            #pragma unroll
            for (int r = 0; r < 4; ++r) p = fmaf(fmaxf(aH[r], 0.f), wh2c[r], p);
            p += __shfl_xor(p, 16, 64);
            p += __shfl_xor(p, 32, 64);
            if (lane == 0) yp[ii & 1][j] = p;
        }

        // ---------------- Phase B (no barrier needed before it) ----------------
        const bool c1 = (ii >= 1) && (ii <= TT);   // h1 commit
        const bool c0 = (ii < TT);                 // h0 commit
        #pragma unroll
        for (int r = 0; r < 4; ++r) {
            // layer-1 combine (lane-local: aX/aG already biased)
            float rr = sigmoid_f(aX[0][r] + aG[0][r]);
            float zz = sigmoid_f(aX[1][r] + aG[1][r]);
            float nn = tanh_f(fmaf(rr, aG[2][r], aX[2][r]));
            float h1n = fmaf(zz, h1p[r] - nn, nn);
            h1p[r] = c1 ? h1n : h1p[r];
            // layer-0 combine (x-side via pinned consts)
            float xr = fmaf(xv, wR[r], bR[r]);
            float xz = fmaf(xv, wZ[r], bZ[r]);
            float xn = fmaf(xv, wN[r], bN[r]);
            float r0 = sigmoid_f(xr + aA[0][r]);
            float z0 = sigmoid_f(xz + aA[1][r]);
            float n0 = tanh_f(fmaf(r0, aA[2][r], xn));
            float h0n = fmaf(z0, h0p[r] - n0, n0);
            h0p[r] = c0 ? h0n : h0p[r];
        }
        if (c == 0) {   // repack new state into the other buffer
            unsigned ph_, pl_;
            const int mp = 8*j + g*2;
            split_pair(h0p[0], h0p[1], ph_, pl_);
            hpk[nbuf][0][0][mp]   = ph_; hpk[nbuf][0][1][mp]   = pl_;
            split_pair(h0p[2], h0p[3], ph_, pl_);
            hpk[nbuf][0][0][mp+1] = ph_; hpk[nbuf][0][1][mp+1] = pl_;
            split_pair(h1p[0], h1p[1], ph_, pl_);
            hpk[nbuf][1][0][mp]   = ph_; hpk[nbuf][1][1][mp]   = pl_;
            split_pair(h1p[2], h1p[3], ph_, pl_);
            hpk[nbuf][1][0][mp+1] = ph_; hpk[nbuf][1][1][mp+1] = pl_;
        }
        __syncthreads();   // single barrier per iteration
    }

    // final hidden states hT[2,B,H] (exact fp32 from register-carried state)
    if (c == 0) {
        #pragma unroll
        for (int r = 0; r < 4; ++r) {
            out[YSZ +           b*HH + 16*j + g*4 + r] = h0p[r];
            out[YSZ + BB*HH +   b*HH + 16*j + g*4 + r] = h1p[r];
        }
    }
}

extern "C" void kernel_launch(void* const* d_in, const int* in_sizes, int n_in,
                              void* d_out, int out_size, void* d_ws, size_t ws_size,
                              hipStream_t stream) {
    const float* x     = (const float*)d_in[0];
    const float* h0in  = (const float*)d_in[1];
    const float* W_ih0 = (const float*)d_in[2];
    const float* W_hh0 = (const float*)d_in[3];
    const float* b_ih0 = (const float*)d_in[4];
    const float* b_hh0 = (const float*)d_in[5];
    const float* W_ih1 = (const float*)d_in[6];
    const float* W_hh1 = (const float*)d_in[7];
    const float* b_ih1 = (const float*)d_in[8];
    const float* b_hh1 = (const float*)d_in[9];
    const float* Wh1   = (const float*)d_in[10];
    const float* bh1   = (const float*)d_in[11];
    const float* Wh2   = (const float*)d_in[12];
    const float* bh2   = (const float*)d_in[13];
    float* out = (float*)d_out;

    gru_fused<<<dim3(BB), dim3(256), 0, stream>>>(
        x, h0in, W_ih0, W_hh0, b_ih0, b_hh0,
        W_ih1, W_hh1, b_ih1, b_hh1, Wh1, bh1, Wh2, bh2, out);
}

// Round 10
// 3329.270 us; speedup vs baseline: 1.0178x; 1.0178x over previous
//
#include <hip/hip_runtime.h>

#define HH 64
#define TT 2048
#define BB 256
#define YSZ (BB*TT)   // y elements before hT in d_out

typedef __attribute__((ext_vector_type(8))) short bf16x8;        // MFMA A/B frag (4 regs)
typedef __attribute__((ext_vector_type(4))) float f32x4;         // MFMA C/D frag
typedef __attribute__((ext_vector_type(4))) unsigned int u32x4;

__device__ __forceinline__ float sigmoid_f(float v) { return 1.0f/(1.0f+__expf(-v)); }
__device__ __forceinline__ float tanh_f(float v)    { return 1.0f - 2.0f/(1.0f+__expf(2.0f*v)); }

// Intrinsic MFMA: compiler models hazards + schedules into latency shadow
// (R9's inline-asm MFMAs forced conservative s_nop padding -> 2x slowdown).
#define MFMA_I(a, b, c) __builtin_amdgcn_mfma_f32_16x16x32_bf16((a), (b), (c), 0, 0, 0)

// Split two fp32 into bf16 hi-pair (truncation) + lo-pair (RNE of residual).
// Pair layout: low16 = even row, high16 = odd row (matches frag k-pair order).
__device__ __forceinline__ void split_pair(float a0, float a1, unsigned& hi, unsigned& lo) {
    unsigned u0 = __float_as_uint(a0) & 0xFFFF0000u;
    unsigned u1 = __float_as_uint(a1) & 0xFFFF0000u;
    hi = (u0 >> 16) | u1;
    float l0 = a0 - __uint_as_float(u0);
    float l1 = a1 - __uint_as_float(u1);
    asm("v_cvt_pk_bf16_f32 %0, %1, %2" : "=v"(lo) : "v"(l0), "v"(l1));
}

// Build hi/lo A-fragments for one (tile,k-half): lane holds row (lane&15),
// k = kh*32 + (lane>>4)*8 + jj  (same k-mapping used for B -> permutation-safe).
__device__ __forceinline__ void load_frag_pair(const float* Wrow, bf16x8& hi8, bf16x8& lo8) {
    #pragma unroll
    for (int jj = 0; jj < 8; ++jj) {
        float f = Wrow[jj];
        unsigned uh = __float_as_uint(f) & 0xFFFF0000u;
        hi8[jj] = (short)(uh >> 16);
        float lo = f - __uint_as_float(uh);
        unsigned ul = __float_as_uint(lo);
        unsigned rr = ul + 0x7FFFu + ((ul >> 16) & 1u);
        lo8[jj] = (short)(rr >> 16);
    }
}

// 256 threads = 4 waves (1/SIMD), 256 blocks (1 seq/CU). Wave j owns gate-row
// triples {16j..16j+16} of r/z/n blocks for all 3 gate matrices + head tile j
// -> every combine is lane-local on the MFMA D-fragments (col=lane&15 is a
// replicated dim). One barrier per iteration; h double-buffered in LDS as
// bf16 hi/lo pairs; exact fp32 h carried in registers. R9 schedule verbatim.
__global__ __launch_bounds__(256, 1)
void gru_fused(const float* __restrict__ x,      // [B,T,1]
               const float* __restrict__ h0in,   // [2,B,H]
               const float* __restrict__ W_ih0,  // [192,1]
               const float* __restrict__ W_hh0,  // [192,64]
               const float* __restrict__ b_ih0,  // [192]
               const float* __restrict__ b_hh0,  // [192]
               const float* __restrict__ W_ih1,  // [192,64]
               const float* __restrict__ W_hh1,  // [192,64]
               const float* __restrict__ b_ih1,  // [192]
               const float* __restrict__ b_hh1,  // [192]
               const float* __restrict__ Wh1,    // [64,64]
               const float* __restrict__ bh1,    // [64]
               const float* __restrict__ Wh2,    // [1,64]
               const float* __restrict__ bh2,    // [1]
               float* __restrict__ out)          // y [B*T] ++ hT [2,B,H]
{
    const int b    = blockIdx.x;
    const int tid  = threadIdx.x;
    const int j    = tid >> 6;        // wave 0..3
    const int lane = tid & 63;
    const int g    = lane >> 4;       // k-chunk / row-group 0..3
    const int c    = lane & 15;       // MFMA col (replicated dim)

    // h state, double-buffered, packed bf16 pairs: [buf][layer][hi/lo][pair m/2]
    __shared__ __align__(16) unsigned int hpk[2][2][2][32];
    __shared__ float yp[2][4];        // head partials, double-buffered
    __shared__ __align__(16) float x_lds[TT];

    // ---- preload x row (coalesced float4) ----
    {
        const float4* xs = reinterpret_cast<const float4*>(x + (size_t)b * TT);
        float4*       xd = reinterpret_cast<float4*>(x_lds);
        #pragma unroll
        for (int k = tid; k < TT / 4; k += 256) xd[k] = xs[k];
    }

    // ---- weight fragments (hi/lo split) ----
    // fA=W_hh0, fX=W_ih1, fG=W_hh1 (12 each: [tile]*4 + [khalf]*2 + [hi/lo]),
    // fH=Wh1 (4). Tile t rowbase = 64*t + 16*j.
    bf16x8 fA[12], fX[12], fG[12], fH[4];
    #pragma unroll
    for (int t = 0; t < 3; ++t)
        #pragma unroll
        for (int kh = 0; kh < 2; ++kh) {
            const size_t ro = (size_t)(64*t + 16*j + c) * HH + kh*32 + g*8;
            load_frag_pair(W_hh0 + ro, fA[t*4+kh*2], fA[t*4+kh*2+1]);
            load_frag_pair(W_ih1 + ro, fX[t*4+kh*2], fX[t*4+kh*2+1]);
            load_frag_pair(W_hh1 + ro, fG[t*4+kh*2], fG[t*4+kh*2+1]);
        }
    #pragma unroll
    for (int kh = 0; kh < 2; ++kh)
        load_frag_pair(Wh1 + (size_t)(16*j + c) * HH + kh*32 + g*8,
                       fH[kh*2], fH[kh*2+1]);

    // ---- bias fragments (used as the C operand of each chain's first MFMA) ----
    f32x4 cA[3], cX[3], cG[3], cH;
    #pragma unroll
    for (int t = 0; t < 3; ++t)
        #pragma unroll
        for (int r = 0; r < 4; ++r) {
            const int row = 64*t + 16*j + g*4 + r;
            cA[t][r] = b_hh0[row];
            cX[t][r] = b_ih1[row];
            cG[t][r] = b_hh1[row];
        }
    #pragma unroll
    for (int r = 0; r < 4; ++r) cH[r] = bh1[16*j + g*4 + r];

    // ---- per-lane scalar constants ----
    float wR[4], wZ[4], wN[4], bR[4], bZ[4], bN[4], wh2c[4];
    #pragma unroll
    for (int r = 0; r < 4; ++r) {
        const int m = 16*j + g*4 + r;
        wR[r] = W_ih0[m];      bR[r] = b_ih0[m];
        wZ[r] = W_ih0[m+64];   bZ[r] = b_ih0[m+64];
        wN[r] = W_ih0[m+128];  bN[r] = b_ih0[m+128];
        wh2c[r] = Wh2[m];
    }
    const float bh2v = bh2[0];

    // ---- h state: fp32 in registers (redundant over c) ----
    float h0p[4], h1p[4];
    #pragma unroll
    for (int r = 0; r < 4; ++r) {
        h0p[r] = h0in[          b*HH + 16*j + g*4 + r];
        h1p[r] = h0in[BB*HH +   b*HH + 16*j + g*4 + r];
    }
    if (c == 0) {   // initial packed state -> buf 0
        unsigned ph_, pl_;
        const int mp = 8*j + g*2;
        split_pair(h0p[0], h0p[1], ph_, pl_);
        hpk[0][0][0][mp]   = ph_; hpk[0][0][1][mp]   = pl_;
        split_pair(h0p[2], h0p[3], ph_, pl_);
        hpk[0][0][0][mp+1] = ph_; hpk[0][0][1][mp+1] = pl_;
        split_pair(h1p[0], h1p[1], ph_, pl_);
        hpk[0][1][0][mp]   = ph_; hpk[0][1][1][mp]   = pl_;
        split_pair(h1p[2], h1p[3], ph_, pl_);
        hpk[0][1][0][mp+1] = ph_; hpk[0][1][1][mp+1] = pl_;
    }
    __syncthreads();

    // Schedule (R9-proven): A(ii) MFMAs read h0=state^ii, h1=state^(ii-1);
    // B(ii) commits h1 (1<=ii<=TT), h0 (ii<TT); y[ii-3] stored at A(ii).
    for (int ii = 0; ii <= TT + 2; ++ii) {
        const int buf = ii & 1, nbuf = buf ^ 1;

        // ---------------- Phase A ----------------
        const float xv = x_lds[ii < TT ? ii : TT-1];
        if (tid == 0 && ii >= 3) {
            const int pb = (ii-1) & 1;
            out[(size_t)b*TT + (ii-3)] =
                yp[pb][0] + yp[pb][1] + yp[pb][2] + yp[pb][3] + bh2v;
        }
        // B fragments (broadcast reads; cols replicated -> col-map immune)
        bf16x8 B0h[2], B0l[2], B1h[2], B1l[2];
        #pragma unroll
        for (int kh = 0; kh < 2; ++kh) {
            const int o = kh*16 + g*4;
            B0h[kh] = __builtin_bit_cast(bf16x8, *(const u32x4*)&hpk[buf][0][0][o]);
            B0l[kh] = __builtin_bit_cast(bf16x8, *(const u32x4*)&hpk[buf][0][1][o]);
            B1h[kh] = __builtin_bit_cast(bf16x8, *(const u32x4*)&hpk[buf][1][0][o]);
            B1l[kh] = __builtin_bit_cast(bf16x8, *(const u32x4*)&hpk[buf][1][1][o]);
        }
        // 3-term split MFMAs, bias frag as first C: Whi@Hhi + Whi@Hlo + Wlo@Hhi
        f32x4 aA[3], aX[3], aG[3], aH;
        #pragma unroll
        for (int t = 0; t < 3; ++t) {
            const int fi = t*4;
            f32x4 acc;
            acc = MFMA_I(fA[fi],   B0h[0], cA[t]);
            acc = MFMA_I(fA[fi],   B0l[0], acc);
            acc = MFMA_I(fA[fi+1], B0h[0], acc);
            acc = MFMA_I(fA[fi+2], B0h[1], acc);
            acc = MFMA_I(fA[fi+2], B0l[1], acc);
            acc = MFMA_I(fA[fi+3], B0h[1], acc);
            aA[t] = acc;
            acc = MFMA_I(fX[fi],   B0h[0], cX[t]);
            acc = MFMA_I(fX[fi],   B0l[0], acc);
            acc = MFMA_I(fX[fi+1], B0h[0], acc);
            acc = MFMA_I(fX[fi+2], B0h[1], acc);
            acc = MFMA_I(fX[fi+2], B0l[1], acc);
            acc = MFMA_I(fX[fi+3], B0h[1], acc);
            aX[t] = acc;
            acc = MFMA_I(fG[fi],   B1h[0], cG[t]);
            acc = MFMA_I(fG[fi],   B1l[0], acc);
            acc = MFMA_I(fG[fi+1], B1h[0], acc);
            acc = MFMA_I(fG[fi+2], B1h[1], acc);
            acc = MFMA_I(fG[fi+2], B1l[1], acc);
            acc = MFMA_I(fG[fi+3], B1h[1], acc);
            aG[t] = acc;
        }
        {
            f32x4 acc;
            acc = MFMA_I(fH[0], B1h[0], cH);
            acc = MFMA_I(fH[0], B1l[0], acc);
            acc = MFMA_I(fH[1], B1h[0], acc);
            acc = MFMA_I(fH[2], B1h[1], acc);
            acc = MFMA_I(fH[2], B1l[1], acc);
            acc = MFMA_I(fH[3], B1h[1], acc);
            aH = acc;
        }
        // head partial: relu dot Wh2, reduce over row-groups
        {
            float p = 0.f;
            #pragma unroll
            for (int r = 0; r < 4; ++r) p = fmaf(fmaxf(aH[r], 0.f), wh2c[r], p);
            p += __shfl_xor(p, 16, 64);
            p += __shfl_xor(p, 32, 64);
            if (lane == 0) yp[ii & 1][j] = p;
        }

        // ---------------- Phase B ----------------
        const bool c1 = (ii >= 1) && (ii <= TT);   // h1 commit
        const bool c0 = (ii < TT);                 // h0 commit
        #pragma unroll
        for (int r = 0; r < 4; ++r) {
            // layer-1 combine (lane-local: aX/aG already biased)
            float rr = sigmoid_f(aX[0][r] + aG[0][r]);
            float zz = sigmoid_f(aX[1][r] + aG[1][r]);
            float nn = tanh_f(fmaf(rr, aG[2][r], aX[2][r]));
            float h1n = fmaf(zz, h1p[r] - nn, nn);
            h1p[r] = c1 ? h1n : h1p[r];
            // layer-0 combine (x-side scalar)
            float xr = fmaf(xv, wR[r], bR[r]);
            float xz = fmaf(xv, wZ[r], bZ[r]);
            float xn = fmaf(xv, wN[r], bN[r]);
            float r0 = sigmoid_f(xr + aA[0][r]);
            float z0 = sigmoid_f(xz + aA[1][r]);
            float n0 = tanh_f(fmaf(r0, aA[2][r], xn));
            float h0n = fmaf(z0, h0p[r] - n0, n0);
            h0p[r] = c0 ? h0n : h0p[r];
        }
        if (c == 0) {   // repack new state into the other buffer
            unsigned ph_, pl_;
            const int mp = 8*j + g*2;
            split_pair(h0p[0], h0p[1], ph_, pl_);
            hpk[nbuf][0][0][mp]   = ph_; hpk[nbuf][0][1][mp]   = pl_;
            split_pair(h0p[2], h0p[3], ph_, pl_);
            hpk[nbuf][0][0][mp+1] = ph_; hpk[nbuf][0][1][mp+1] = pl_;
            split_pair(h1p[0], h1p[1], ph_, pl_);
            hpk[nbuf][1][0][mp]   = ph_; hpk[nbuf][1][1][mp]   = pl_;
            split_pair(h1p[2], h1p[3], ph_, pl_);
            hpk[nbuf][1][0][mp+1] = ph_; hpk[nbuf][1][1][mp+1] = pl_;
        }
        __syncthreads();   // single barrier per iteration
    }

    // final hidden states hT[2,B,H] (exact fp32 from register-carried state)
    if (c == 0) {
        #pragma unroll
        for (int r = 0; r < 4; ++r) {
            out[YSZ +           b*HH + 16*j + g*4 + r] = h0p[r];
            out[YSZ + BB*HH +   b*HH + 16*j + g*4 + r] = h1p[r];
        }
    }
}

extern "C" void kernel_launch(void* const* d_in, const int* in_sizes, int n_in,
                              void* d_out, int out_size, void* d_ws, size_t ws_size,
                              hipStream_t stream) {
    const float* x     = (const float*)d_in[0];
    const float* h0in  = (const float*)d_in[1];
    const float* W_ih0 = (const float*)d_in[2];
    const float* W_hh0 = (const float*)d_in[3];
    const float* b_ih0 = (const float*)d_in[4];
    const float* b_hh0 = (const float*)d_in[5];
    const float* W_ih1 = (const float*)d_in[6];
    const float* W_hh1 = (const float*)d_in[7];
    const float* b_ih1 = (const float*)d_in[8];
    const float* b_hh1 = (const float*)d_in[9];
    const float* Wh1   = (const float*)d_in[10];
    const float* bh1   = (const float*)d_in[11];
    const float* Wh2   = (const float*)d_in[12];
    const float* bh2   = (const float*)d_in[13];
    float* out = (float*)d_out;

    gru_fused<<<dim3(BB), dim3(256), 0, stream>>>(
        x, h0in, W_ih0, W_hh0, b_ih0, b_hh0,
        W_ih1, W_hh1, b_ih1, b_hh1, Wh1, bh1, Wh2, bh2, out);
}